// Round 16
// baseline (82.853 us; speedup 1.0000x reference)
//
#include <hip/hip_runtime.h>
#include <stdint.h>

#define HID 1024
#define BB 4
#define TT 2048
#define M_ROWS (BB * TT)  // 8192

typedef __attribute__((ext_vector_type(8))) short s16x8;
typedef __attribute__((ext_vector_type(4))) float f32x4;

__device__ __forceinline__ unsigned short f2bf(float f) {
  unsigned u = __float_as_uint(f);
  u += 0x7fffu + ((u >> 16) & 1u);  // RNE
  return (unsigned short)(u >> 16);
}

__device__ __forceinline__ s16x8 cvt8(float4 a, float4 b) {
  s16x8 v;
  v[0] = (short)f2bf(a.x); v[1] = (short)f2bf(a.y); v[2] = (short)f2bf(a.z); v[3] = (short)f2bf(a.w);
  v[4] = (short)f2bf(b.x); v[5] = (short)f2bf(b.y); v[6] = (short)f2bf(b.z); v[7] = (short)f2bf(b.w);
  return v;
}

__device__ __forceinline__ void gload16(const void* g, void* l) {
  __builtin_amdgcn_global_load_lds(
      (const __attribute__((address_space(1))) unsigned int*)g,
      (__attribute__((address_space(3))) unsigned int*)l, 16, 0, 0);
}

// ------- weight prep: z=0 transpose Wv [in][out] -> bf16 [out][in]; z=1 cvt Wo -------
__global__ void prep_weights(const float* __restrict__ Wv, const float* __restrict__ Wo,
                             unsigned short* __restrict__ wvt, unsigned short* __restrict__ wob) {
  int tx = threadIdx.x, ty = threadIdx.y;
  int i0 = blockIdx.y * 32, o0 = blockIdx.x * 32;
  if (blockIdx.z == 1) {
#pragma unroll
    for (int k = 0; k < 4; ++k)
      wob[(size_t)(i0 + ty + 8 * k) * HID + o0 + tx] = f2bf(Wo[(size_t)(i0 + ty + 8 * k) * HID + o0 + tx]);
    return;
  }
  __shared__ float tile[32][33];
#pragma unroll
  for (int k = 0; k < 4; ++k)
    tile[ty + 8 * k][tx] = Wv[(size_t)(i0 + ty + 8 * k) * HID + o0 + tx];
  __syncthreads();
#pragma unroll
  for (int k = 0; k < 4; ++k)
    wvt[(size_t)(o0 + ty + 8 * k) * HID + i0 + tx] = f2bf(tile[tx][ty + 8 * k]);
}

// ======== wide-wave GEMM: C[M,N] = A[M,K] * Bt[N,K]^T ========
// BM=256, BN=128, BK=64, 256 thr = 4 waves (2M x 2N), per-wave 128x64
// (acc 8x4, 64 MFMA/tile/wave) -> 0.375 LDS-reads/MFMA: per-CU LDS port
// (~1300 cyc/K-tile) finally BELOW the MFMA pole (1242 cyc). 96 KB LDS
// ring-2 -> 1 block/CU. r8's 1-barrier/K-tile schedule. XOR slot swizzle
// (slot ^ (row&7)) on A and B (2-way max = free, mod-32 checked).
// Grid 256; XCD map: each M-supertile's 8 N-blocks on one XCD (x L2 reuse).
// MODE 0: A = x fp32, reg-staged + cvt + swizzled ds_write (per half-tile);
//         out bf16 scattered to the permuted ctx layout (einsum collapse:
//         ctx[b,h,t,d] = v[b,t,h,d] since sum_l softmax = 1).
// MODE 1: A = bf16 via gload_lds; out fp32 row-major.
template <int MODE>
__global__ __launch_bounds__(256) void gemm_wide(const void* __restrict__ Av,
                                                 const unsigned short* __restrict__ Bt,
                                                 void* __restrict__ outBase) {
  constexpr int Kd = 1024;
  constexpr int NT = 16;
  const int tid = threadIdx.x;
  const int lane = tid & 63;
  const int w = tid >> 6;
  const int wm = w >> 1, wn = w & 1;
  const int lr = lane & 15, lg = lane >> 4;
  const int lin = blockIdx.x;
  const int wid = (lin & 7) * 32 + (lin >> 3);  // XCD-bijective (256 = 8 x 32)
  const int blockM = (wid >> 3) * 256;
  const int blockN = (wid & 7) * 128;

  __shared__ __align__(16) short Abuf[2][256 * 64];  // 64 KB
  __shared__ __align__(16) short Bbuf[2][128 * 64];  // 32 KB

  f32x4 acc[8][4] = {};
  const float* Af32 = (const float*)Av;
  const unsigned short* Ab16 = (const unsigned short*)Av;
  const unsigned short* pb = Bt + (size_t)blockN * Kd;

  // ---- B staging (gload_lds, 4 granule passes) ----
  // granule g = p*256 + tid: row = p*32 + (tid>>3), slot = tid&7.
  // LDS linear (row, slot) <- global (row, slot ^ (row&7)); row&7 pass-invariant.
  const int gr8 = tid >> 3;         // 0..31
  const int gs8 = ((tid & 7) ^ (gr8 & 7)) * 8;
  auto stageB = [&](int bi, int kt) {
#pragma unroll
    for (int p = 0; p < 4; ++p)
      gload16(pb + (size_t)(p * 32 + gr8) * Kd + kt * 64 + gs8,
              (char*)Bbuf[bi] + (size_t)(p * 256 + w * 64) * 16);
  };
  // ---- A staging MODE 1 (gload_lds, 8 passes over 256 rows) ----
  auto stageA16 = [&](int bi, int kt) {
#pragma unroll
    for (int p = 0; p < 8; ++p)
      gload16(Ab16 + (size_t)(blockM + p * 32 + gr8) * Kd + kt * 64 + gs8,
              (char*)Abuf[bi] + (size_t)(p * 256 + w * 64) * 16);
  };
  // ---- A staging MODE 0 (fp32 reg -> cvt -> swizzled ds_write), per k-half ----
  // thread -> rows u*64 + (tid>>2) (u=0..3), 8 floats at col (tid&3)*8 of the half.
  const int ar4 = tid >> 2;   // 0..63
  const int as4 = tid & 3;    // granule-slot within half
  float4 areg[8];
  auto loadA32h = [&](int kt, int h) {
#pragma unroll
    for (int u = 0; u < 4; ++u) {
      const float* s = Af32 + (size_t)(blockM + u * 64 + ar4) * Kd + kt * 64 + h * 32 + as4 * 8;
      areg[u * 2] = *(const float4*)s;
      areg[u * 2 + 1] = *(const float4*)(s + 4);
    }
  };
  auto writeA32h = [&](int bi, int h) {
#pragma unroll
    for (int u = 0; u < 4; ++u) {
      int row = u * 64 + ar4;
      int phys = (h * 4 + as4) ^ (row & 7);
      *(s16x8*)(Abuf[bi] + row * 64 + phys * 8) = cvt8(areg[u * 2], areg[u * 2 + 1]);
    }
  };

  // ---- compute one k-half: 8 A frags + 4 B frags -> 32 MFMA ----
  auto computeH = [&](const short* Ab, const short* Bb, int h) {
    const int coff = ((h * 4 + lg) ^ (lr & 7)) * 8;
    s16x8 af[8], bf[4];
#pragma unroll
    for (int mi = 0; mi < 8; ++mi)
      af[mi] = *(const s16x8*)(Ab + (wm * 128 + mi * 16 + lr) * 64 + coff);
#pragma unroll
    for (int ni = 0; ni < 4; ++ni)
      bf[ni] = *(const s16x8*)(Bb + (wn * 64 + ni * 16 + lr) * 64 + coff);
    __builtin_amdgcn_s_setprio(1);
#pragma unroll
    for (int mi = 0; mi < 8; ++mi)
#pragma unroll
      for (int ni = 0; ni < 4; ++ni)
        acc[mi][ni] = __builtin_amdgcn_mfma_f32_16x16x32_bf16(af[mi], bf[ni], acc[mi][ni], 0, 0, 0);
    __builtin_amdgcn_s_setprio(0);
  };

  // ---- prologue: tile 0 ----
  if constexpr (MODE == 0) {
    loadA32h(0, 0);
    stageB(0, 0);
    writeA32h(0, 0);
    loadA32h(0, 1);
    writeA32h(0, 1);
  } else {
    stageA16(0, 0);
    stageB(0, 0);
  }
  __syncthreads();

  for (int t = 0; t < NT; ++t) {
    const short* Ab = Abuf[t & 1];
    const short* Bb = Bbuf[t & 1];
    const int bn = (t + 1) & 1;
    const bool more = (t + 1 < NT);
    if constexpr (MODE == 0) {
      if (more) {
        loadA32h(t + 1, 0);   // VMEM issued; lands under MFMA h0
        stageB(bn, t + 1);
      }
      computeH(Ab, Bb, 0);
      if (more) {
        writeA32h(bn, 0);
        loadA32h(t + 1, 1);
      }
      computeH(Ab, Bb, 1);
      if (more) writeA32h(bn, 1);
    } else {
      if (more) {
        stageA16(bn, t + 1);
        stageB(bn, t + 1);
      }
      computeH(Ab, Bb, 0);
      computeH(Ab, Bb, 1);
    }
    if (more) __syncthreads();
  }

  if constexpr (MODE == 0) {
    // permuted ctx layout (einsum collapse)
    unsigned short* out = (unsigned short*)outBase;
#pragma unroll
    for (int mi = 0; mi < 8; ++mi) {
#pragma unroll
      for (int ni = 0; ni < 4; ++ni) {
        int n = blockN + wn * 64 + ni * 16 + lr;
        int h = n >> 6, d = n & 63;
#pragma unroll
        for (int j = 0; j < 4; ++j) {
          int m = blockM + wm * 128 + mi * 16 + lg * 4 + j;
          int b = m >> 11, tq = m & 2047;
          size_t row = (size_t)b * TT + h * 128 + (tq >> 4);
          out[row * HID + (tq & 15) * 64 + d] = f2bf(acc[mi][ni][j]);
        }
      }
    }
  } else {
    float* out = (float*)outBase;
#pragma unroll
    for (int mi = 0; mi < 8; ++mi) {
#pragma unroll
      for (int ni = 0; ni < 4; ++ni) {
        int n = blockN + wn * 64 + ni * 16 + lr;
#pragma unroll
        for (int j = 0; j < 4; ++j) {
          int m = blockM + wm * 128 + mi * 16 + lg * 4 + j;
          out[(size_t)m * HID + n] = acc[mi][ni][j];
        }
      }
    }
  }
}

extern "C" void kernel_launch(void* const* d_in, const int* in_sizes, int n_in,
                              void* d_out, int out_size, void* d_ws, size_t ws_size,
                              hipStream_t stream) {
  const float* x = (const float*)d_in[0];
  // d_in[1] = mask: irrelevant — additive finite mask cannot change sum_l softmax = 1,
  // and the reference's einsum 'bhtl,bthd->bhtd' contracts l over A alone.
  // d_in[2] = Wq, d_in[3] = Wk: unused for the same reason.
  const float* Wv = (const float*)d_in[4];
  const float* Wo = (const float*)d_in[5];

  char* ws = (char*)d_ws;
  unsigned short* Mb  = (unsigned short*)(ws);                 // [0,16M): permuted ctx bf16
  unsigned short* wvt = (unsigned short*)(ws + (16u << 20));   // [16,18M): Wv^T bf16 [out][in]
  unsigned short* wob = (unsigned short*)(ws + (18u << 20));   // [18,20M): Wo bf16 ([out][in] already)

  prep_weights<<<dim3(32, 32, 2), dim3(32, 8), 0, stream>>>(Wv, Wo, wvt, wob);
  gemm_wide<0><<<256, 256, 0, stream>>>(x, wvt, Mb);
  gemm_wide<1><<<256, 256, 0, stream>>>(Mb, wob, d_out);
}